// Round 9
// baseline (101.294 us; speedup 1.0000x reference)
//
#include <hip/hip_runtime.h>
#include <hip/hip_bf16.h>

// GQA paged-prefill attention, MI355X gfx950.
// Causal mask j<=i over concat(past,new) => only first Q_LEN (=1024) gathered
// past tokens are live. Flash-attention over tokens 0..1023 of paged cache.
//
// R9: barrier-free wave-independent design. prep_kv writes LINEAR bf16
// K tiles [64][128] and V^T tiles [128][64] to ws (4MB total = L2-resident).
// attn_main: each wave owns (qt, head, 16-row group), loops its kv tiles
// reading K/V fragments DIRECTLY from L2 (16B short8 loads, 64B-coalesced).
// No __syncthreads, no LDS staging, no kv-split/combine. Block = 4 waves =
// 4 GQA heads sharing one kv head (identical K/V addresses -> L1 reuse).
// Per-wave 2KB LDS only for the P relayout (same-wave lgkmcnt).

#define Q_STRIDE 4096
#define SCALE 0.08838834764831845f
#define RESCALE_THR 8.0f
#define KSW_TILE 16384                 // bytes per (hkv, jb) tile
#define VSW_OFF (2 * 1024 * 1024)      // V^T tiles at +2MB

typedef short short8 __attribute__((ext_vector_type(8)));
typedef float f32x4 __attribute__((ext_vector_type(4)));
typedef unsigned short ushort_t;
typedef unsigned int uint_t;

__device__ __forceinline__ ushort_t f2bf(float f) {
    return __builtin_bit_cast(ushort_t, __float2bfloat16(f));
}
__device__ __forceinline__ uint_t pk2(float a, float b) {
    return (uint_t)f2bf(a) | ((uint_t)f2bf(b) << 16);
}

// ---------------- prep: paged fp32 -> dense linear bf16 ----------------
__launch_bounds__(256)
__global__ void prep_kv(const float* __restrict__ kvc,
                        const int* __restrict__ bt,
                        char* __restrict__ wsb)
{
    __shared__ float sVt[64 * 128];
    const int blk = blockIdx.x;        // 128 blocks = hkv(8) x jb(16)
    const int hkv = blk >> 4;
    const int jb  = blk & 15;
    const int tid = threadIdx.x;
    char* kout = wsb + (size_t)(hkv * 16 + jb) * KSW_TILE;
    char* vout = wsb + VSW_OFF + (size_t)(hkv * 16 + jb) * KSW_TILE;

    // K: [t 64][d 128] bf16 linear
#pragma unroll
    for (int i = 0; i < 4; ++i) {
        const int u = tid + i * 256;   // t(64) x c(16)
        const int t = u >> 4, c = u & 15;
        const int gtok = jb * 64 + t;
        const int page = bt[gtok >> 4];
        const float* src = kvc + (size_t)page * 32768 + (size_t)hkv * 2048
                         + (gtok & 15) * 128 + c * 8;
        float4 a = *(const float4*)src;
        float4 b = *(const float4*)(src + 4);
        uint4 p;
        p.x = pk2(a.x, a.y); p.y = pk2(a.z, a.w);
        p.z = pk2(b.x, b.y); p.w = pk2(b.z, b.w);
        *(uint4*)(kout + t * 256 + c * 16) = p;
    }
    // V: coalesced fp32 read -> LDS
#pragma unroll
    for (int i = 0; i < 8; ++i) {
        const int u = tid + i * 256;   // t(64) x c4(32)
        const int t = u >> 5, c4 = u & 31;
        const int gtok = jb * 64 + t;
        const int page = bt[gtok >> 4];
        const float* src = kvc + (size_t)page * 32768 + 16384
                         + (size_t)hkv * 2048 + (gtok & 15) * 128 + c4 * 4;
        *(float4*)(sVt + t * 128 + c4 * 4) = *(const float4*)src;
    }
    __syncthreads();
    // V^T: [d 128][t 64] bf16 linear
#pragma unroll
    for (int i = 0; i < 4; ++i) {
        const int u = tid + i * 256;   // d(128) x ch(8)
        const int d = u >> 3, ch = u & 7;
        float v[8];
#pragma unroll
        for (int k = 0; k < 8; ++k) v[k] = sVt[(8 * ch + k) * 128 + d];
        uint4 p;
        p.x = pk2(v[0], v[1]); p.y = pk2(v[2], v[3]);
        p.z = pk2(v[4], v[5]); p.w = pk2(v[6], v[7]);
        *(uint4*)(vout + d * 128 + 16 * ch) = p;
    }
}

// ---------------- main attention ----------------
__launch_bounds__(256)
__global__ void attn_main(const float* __restrict__ q,
                          const char* __restrict__ kvbf,
                          float* __restrict__ out)
{
    __shared__ __align__(16) char sP[4][2048];   // per-wave P buffer

    const int bid = blockIdx.x;        // 512 = qt(16) x hkv(8) x rg(4)
    const int qt  = 15 - (bid >> 5);   // long blocks first
    const int hkv = (bid >> 2) & 7;
    const int rg  = bid & 3;
    const int tid  = threadIdx.x;
    const int w    = tid >> 6;
    const int lane = tid & 63;
    const int l15  = lane & 15;
    const int lhi  = lane >> 4;
    const int h    = hkv * 4 + w;      // this wave's query head

    // ---- Q fragments (SCALE folded): wave rows qt*64 + rg*16 + l15
    short8 qf[4];
    {
        const int qrow = qt * 64 + rg * 16 + l15;
        const float* qp = q + (size_t)qrow * Q_STRIDE + h * 128;
#pragma unroll
        for (int s = 0; s < 4; ++s) {
            const int d0 = s * 32 + lhi * 8;
            float4 a = *(const float4*)(qp + d0);
            float4 b = *(const float4*)(qp + d0 + 4);
            short8 v;
            v[0] = (short)f2bf(a.x * SCALE); v[1] = (short)f2bf(a.y * SCALE);
            v[2] = (short)f2bf(a.z * SCALE); v[3] = (short)f2bf(a.w * SCALE);
            v[4] = (short)f2bf(b.x * SCALE); v[5] = (short)f2bf(b.y * SCALE);
            v[6] = (short)f2bf(b.z * SCALE); v[7] = (short)f2bf(b.w * SCALE);
            qf[s] = v;
        }
    }

    f32x4 acc[8];
#pragma unroll
    for (int n2 = 0; n2 < 8; ++n2) acc[n2] = (f32x4){0.f, 0.f, 0.f, 0.f};
    float m_run[4]  = {-1e30f, -1e30f, -1e30f, -1e30f};
    float l_part[4] = {0.f, 0.f, 0.f, 0.f};

    char* pb = sP[w];
    const int kfb = (l15 * 256) + (lhi * 16);   // K frag base byte (n=s=0)
    const int vfb = (l15 * 128) + (lhi * 16);   // V frag base byte (n2=s2=0)

    for (int jb = 0; jb <= qt; ++jb) {
        const char* kt = kvbf + (size_t)(hkv * 16 + jb) * KSW_TILE;
        const char* vt = kt + VSW_OFF;

        // ---- K fragments direct from L2 (64B-coalesced per (tok, s))
        short8 kb[4][4];
#pragma unroll
        for (int s = 0; s < 4; ++s)
#pragma unroll
            for (int n = 0; n < 4; ++n)
                kb[s][n] = *(const short8*)(kt + kfb + n * 4096 + s * 64);

        // ---- S = Q K^T
        f32x4 sacc[4];
#pragma unroll
        for (int n = 0; n < 4; ++n) sacc[n] = (f32x4){0.f, 0.f, 0.f, 0.f};
#pragma unroll
        for (int s = 0; s < 4; ++s)
#pragma unroll
            for (int n = 0; n < 4; ++n)
                sacc[n] = __builtin_amdgcn_mfma_f32_16x16x32_bf16(qf[s], kb[s][n], sacc[n], 0, 0, 0);

        // ---- V fragments issued now; latency hides under softmax
        short8 vb[2][8];
#pragma unroll
        for (int s2 = 0; s2 < 2; ++s2)
#pragma unroll
            for (int n2 = 0; n2 < 8; ++n2)
                vb[s2][n2] = *(const short8*)(vt + vfb + n2 * 2048 + s2 * 64);

        // ---- softmax with deferred max, in place
        const bool diag = (jb == qt);
        if (diag) {
#pragma unroll
            for (int n = 0; n < 4; ++n)
#pragma unroll
                for (int j = 0; j < 4; ++j) {
                    const int tok = jb * 64 + n * 16 + l15;
                    const int qg  = qt * 64 + rg * 16 + lhi * 4 + j;
                    if (tok > qg) sacc[n][j] = -1e30f;
                }
        }
#pragma unroll
        for (int j = 0; j < 4; ++j) {
            float lmax = fmaxf(fmaxf(sacc[0][j], sacc[1][j]),
                               fmaxf(sacc[2][j], sacc[3][j]));
            if (__any(lmax > m_run[j] + RESCALE_THR)) {
                float mt = lmax;
#pragma unroll
                for (int off = 1; off < 16; off <<= 1)
                    mt = fmaxf(mt, __shfl_xor(mt, off));
                const float mn = fmaxf(m_run[j], mt);
                const float alpha = __expf(m_run[j] - mn);
                m_run[j] = mn;
                l_part[j] *= alpha;
#pragma unroll
                for (int n2 = 0; n2 < 8; ++n2) acc[n2][j] *= alpha;
            }
            float ls = 0.f;
#pragma unroll
            for (int n = 0; n < 4; ++n) {
                float p = __expf(sacc[n][j] - m_run[j]);
                sacc[n][j] = p;
                ls += p;
            }
            l_part[j] += ls;
        }

        // ---- P -> per-wave LDS (A-fragment relayout); same-wave ordering
#pragma unroll
        for (int n = 0; n < 4; ++n)
#pragma unroll
            for (int j = 0; j < 4; ++j) {
                const int r = lhi * 4 + j;
                const uint_t byte = (uint_t)(r * 128)
                    + (((uint_t)((n * 16 + l15) * 2)) ^ ((uint_t)((r & 7) << 4)));
                *(ushort_t*)(pb + byte) = f2bf(sacc[n][j]);
            }

        // ---- O += P V
#pragma unroll
        for (int s2 = 0; s2 < 2; ++s2) {
            const uint_t pbyte = (uint_t)(l15 * 128)
                + (((uint_t)((s2 * 32 + lhi * 8) * 2)) ^ ((uint_t)((l15 & 7) << 4)));
            short8 pa = *(const short8*)(pb + pbyte);
#pragma unroll
            for (int n2 = 0; n2 < 8; ++n2)
                acc[n2] = __builtin_amdgcn_mfma_f32_16x16x32_bf16(pa, vb[s2][n2], acc[n2], 0, 0, 0);
        }
    }

    // ---- epilogue: reduce l over the 16-lane row group, store normalized
#pragma unroll
    for (int j = 0; j < 4; ++j) {
        float lsum = l_part[j];
#pragma unroll
        for (int off = 1; off < 16; off <<= 1)
            lsum += __shfl_xor(lsum, off);
        const float inv = 1.0f / lsum;
        const int qg = qt * 64 + rg * 16 + lhi * 4 + j;
        float* dst = out + (size_t)qg * Q_STRIDE + h * 128;
#pragma unroll
        for (int n2 = 0; n2 < 8; ++n2)
            dst[n2 * 16 + l15] = acc[n2][j] * inv;
    }
}

extern "C" void kernel_launch(void* const* d_in, const int* in_sizes, int n_in,
                              void* d_out, int out_size, void* d_ws, size_t ws_size,
                              hipStream_t stream) {
    const float* q   = (const float*)d_in[0];
    // d_in[1] (k) and d_in[2] (v) are dead under the reference's causal mask.
    const float* kvc = (const float*)d_in[3];
    const int*   bt  = (const int*)d_in[4];
    float* out = (float*)d_out;
    char*  wsb = (char*)d_ws;
    prep_kv<<<dim3(128), dim3(256), 0, stream>>>(kvc, bt, wsb);
    attn_main<<<dim3(512), dim3(256), 0, stream>>>(q, wsb, out);
}

// Round 11
// 58.570 us; speedup vs baseline: 1.7295x; 1.7295x over previous
//
#include <hip/hip_runtime.h>
#include <hip/hip_bf16.h>

// GQA paged-prefill attention, MI355X gfx950.
// Causal mask j<=i over concat(past,new) => only first Q_LEN (=1024) gathered
// past tokens are live. Flash-attention over tokens 0..1023 of paged cache.
//
// R11 = R10 with the head-index bug fixed: in the split range (bid<512),
// h = (bid>>1)&31 (R10 used bid&31, duplicating even heads in half0 and
// orphaning odd heads). KVBLK=32, 36KB LDS -> 4 blocks/CU, 4 independent
// wave streams per SIMD. qt>=8 split into two equal halves; qt<8 direct.

#define Q_STRIDE 4096
#define SCALE 0.08838834764831845f
#define RESCALE_THR 8.0f
#define KSW_TILE 16384                     // bytes per (hkv, 64-tok tile)
#define VSW_OFF  (2 * 1024 * 1024)         // V tiles at +2MB
#define ACC1_OFF (4 * 1024 * 1024)         // half1 acc bf16: 16384 rows x 256B
#define ML0_OFF  (ACC1_OFF + 16384 * 256)  // half0 (m,l): 16384 x 8B
#define ML1_OFF  (ML0_OFF + 16384 * 8)     // half1 (m,l): 16384 x 8B

typedef short short8 __attribute__((ext_vector_type(8)));
typedef float f32x4 __attribute__((ext_vector_type(4)));
typedef unsigned short ushort_t;
typedef unsigned int uint_t;

__device__ __forceinline__ ushort_t f2bf(float f) {
    return __builtin_bit_cast(ushort_t, __float2bfloat16(f));
}
__device__ __forceinline__ uint_t pk2(float a, float b) {
    return (uint_t)f2bf(a) | ((uint_t)f2bf(b) << 16);
}
__device__ __forceinline__ float bf2f(ushort_t u) {
    uint_t x = ((uint_t)u) << 16;
    return __builtin_bit_cast(float, x);
}

// ---------------- prep: paged fp32 -> dense swizzled bf16 ----------------
__launch_bounds__(256)
__global__ void prep_kv(const float* __restrict__ kvc,
                        const int* __restrict__ bt,
                        char* __restrict__ wsb)
{
    __shared__ float sVt[64 * 128];
    const int blk = blockIdx.x;        // 128 blocks = hkv(8) x jb(16)
    const int hkv = blk >> 4;
    const int jb  = blk & 15;
    const int tid = threadIdx.x;
    char* kout = wsb + (size_t)(hkv * 16 + jb) * KSW_TILE;
    char* vout = wsb + VSW_OFF + (size_t)(hkv * 16 + jb) * KSW_TILE;

    // K: [t 64][d 128] bf16, 16B chunk c at byte t*256 + ((c*16)^((t&7)<<4))
    // (t<32 lands in the first 8KB => 32-tok sub-tiles are contiguous)
#pragma unroll
    for (int i = 0; i < 4; ++i) {
        const int u = tid + i * 256;   // t(64) x c(16)
        const int t = u >> 4, c = u & 15;
        const int gtok = jb * 64 + t;
        const int page = bt[gtok >> 4];
        const float* src = kvc + (size_t)page * 32768 + (size_t)hkv * 2048
                         + (gtok & 15) * 128 + c * 8;
        float4 a = *(const float4*)src;
        float4 b = *(const float4*)(src + 4);
        uint4 p;
        p.x = pk2(a.x, a.y); p.y = pk2(a.z, a.w);
        p.z = pk2(b.x, b.y); p.w = pk2(b.z, b.w);
        *(uint4*)(kout + t * 256 + ((c * 16) ^ ((t & 7) << 4))) = p;
    }
    // V: coalesced fp32 read -> LDS ([t][d])
#pragma unroll
    for (int i = 0; i < 8; ++i) {
        const int u = tid + i * 256;   // t(64) x c4(32)
        const int t = u >> 5, c4 = u & 31;
        const int gtok = jb * 64 + t;
        const int page = bt[gtok >> 4];
        const float* src = kvc + (size_t)page * 32768 + 16384
                         + (size_t)hkv * 2048 + (gtok & 15) * 128 + c4 * 4;
        *(float4*)(sVt + t * 128 + c4 * 4) = *(const float4*)src;
    }
    __syncthreads();
    // V^T halves: [half 2][d 128][t 32] bf16, 16B chunk ch2 (8 toks) at
    // byte half*8192 + d*64 + ((ch2*16)^((d&3)<<4))
#pragma unroll
    for (int i = 0; i < 4; ++i) {
        const int u = tid + i * 256;   // d(128) x ch(8)
        const int d = u >> 3, ch = u & 7;
        const int half = ch >> 2, ch2 = ch & 3;
        float v[8];
#pragma unroll
        for (int k = 0; k < 8; ++k)
            v[k] = sVt[(half * 32 + ch2 * 8 + k) * 128 + d];
        uint4 p;
        p.x = pk2(v[0], v[1]); p.y = pk2(v[2], v[3]);
        p.z = pk2(v[4], v[5]); p.w = pk2(v[6], v[7]);
        *(uint4*)(vout + half * 8192 + d * 64 + ((ch2 * 16) ^ ((d & 3) << 4))) = p;
    }
}

// ---------------- main attention ----------------
#define GLL16(G, L) __builtin_amdgcn_global_load_lds(                         \
    (const uint_t __attribute__((address_space(1)))*)(G),                     \
    (uint_t __attribute__((address_space(3)))*)(L), 16, 0, 0)

// Stage 32-tok sub-tile JB2 (8KB K + 8KB V); 4 waves x 2KB each.
#define STAGE(JB2, KB, VB) {                                                  \
    const char* ks_ = kvbf + (size_t)hkv * 262144 + (size_t)(JB2) * 8192      \
                    + w * 2048 + lane * 16;                                   \
    GLL16(ks_,                  (KB) + w * 2048);                             \
    GLL16(ks_ + 1024,           (KB) + w * 2048 + 1024);                      \
    GLL16(ks_ + VSW_OFF,        (VB) + w * 2048);                             \
    GLL16(ks_ + VSW_OFF + 1024, (VB) + w * 2048 + 1024);                      \
}

__launch_bounds__(256)
__global__ void attn_main(const float* __restrict__ q,
                          const char* __restrict__ kvbf,
                          float* __restrict__ out,
                          char* __restrict__ wsb)
{
    __shared__ __align__(16) char sK[2][8192];
    __shared__ __align__(16) char sV[2][8192];
    __shared__ __align__(16) char sP[4][1024];

    const int bid = blockIdx.x;
    // bid 0..511: halves of qt>=8 (long first); 512..767: direct qt<8
    int qt, jb0, jb1, mode, h;         // mode 0 direct, 1 half0, 2 half1
    if (bid < 512) {
        const int half = bid & 1;
        const int idx  = bid >> 1;     // 0..255 carries (qt, h)
        qt  = 15 - (idx >> 5);         // 15..8
        h   = idx & 31;                // FIXED (R10 used bid&31)
        const int nt = qt + 1;         // sub-tiles per half (equal halves)
        jb0 = half ? nt : 0;
        jb1 = half ? 2 * nt : nt;
        mode = half ? 2 : 1;
    } else {
        const int idx2 = bid - 512;
        qt  = 7 - (idx2 >> 5);         // 7..0
        h   = idx2 & 31;
        jb0 = 0; jb1 = 2 * (qt + 1);
        mode = 0;
    }
    const int hkv = h >> 2;
    const int tid  = threadIdx.x;
    const int w    = tid >> 6;
    const int lane = tid & 63;
    const int l15  = lane & 15;
    const int lhi  = lane >> 4;
    const int rg   = w;                // row group: rows rg*16..+15

    // ---- Q fragments (SCALE folded): wave rows qt*64 + rg*16 + l15
    short8 qf[4];
    {
        const int qrow = qt * 64 + rg * 16 + l15;
        const float* qp = q + (size_t)qrow * Q_STRIDE + h * 128;
#pragma unroll
        for (int s = 0; s < 4; ++s) {
            const int d0 = s * 32 + lhi * 8;
            float4 a = *(const float4*)(qp + d0);
            float4 b = *(const float4*)(qp + d0 + 4);
            short8 v;
            v[0] = (short)f2bf(a.x * SCALE); v[1] = (short)f2bf(a.y * SCALE);
            v[2] = (short)f2bf(a.z * SCALE); v[3] = (short)f2bf(a.w * SCALE);
            v[4] = (short)f2bf(b.x * SCALE); v[5] = (short)f2bf(b.y * SCALE);
            v[6] = (short)f2bf(b.z * SCALE); v[7] = (short)f2bf(b.w * SCALE);
            qf[s] = v;
        }
    }

    f32x4 acc[8];
#pragma unroll
    for (int n2 = 0; n2 < 8; ++n2) acc[n2] = (f32x4){0.f, 0.f, 0.f, 0.f};
    float m_run[4]  = {-1e30f, -1e30f, -1e30f, -1e30f};
    float l_part[4] = {0.f, 0.f, 0.f, 0.f};

    STAGE(jb0, sK[0], sV[0])
    __syncthreads();

    char* pb = sP[w];
    for (int jb2 = jb0; jb2 < jb1; ++jb2) {
        const int cur = (jb2 - jb0) & 1;
        char* kbuf = sK[cur];
        char* vbuf = sV[cur];
        const bool pf = (jb2 + 1 < jb1);
        if (pf) {
            STAGE(jb2 + 1, sK[cur ^ 1], sV[cur ^ 1])
        }

        // ---- S = Q K^T (32 tokens)
        f32x4 sacc[2];
#pragma unroll
        for (int n = 0; n < 2; ++n) sacc[n] = (f32x4){0.f, 0.f, 0.f, 0.f};
#pragma unroll
        for (int s = 0; s < 4; ++s) {
#pragma unroll
            for (int n = 0; n < 2; ++n) {
                const int tok = n * 16 + l15;
                const uint_t byte = (uint_t)(tok * 256)
                    + (((uint_t)((s * 32 + lhi * 8) * 2)) ^ ((uint_t)((tok & 7) << 4)));
                short8 kb = *(const short8*)(kbuf + byte);
                sacc[n] = __builtin_amdgcn_mfma_f32_16x16x32_bf16(qf[s], kb, sacc[n], 0, 0, 0);
            }
        }

        // ---- softmax with deferred max, in place
        if (jb2 >= 2 * qt) {           // diagonal 64-tile
#pragma unroll
            for (int n = 0; n < 2; ++n)
#pragma unroll
                for (int j = 0; j < 4; ++j) {
                    const int tok = jb2 * 32 + n * 16 + l15;
                    const int qg  = qt * 64 + rg * 16 + lhi * 4 + j;
                    if (tok > qg) sacc[n][j] = -1e30f;
                }
        }
#pragma unroll
        for (int j = 0; j < 4; ++j) {
            float lmax = fmaxf(sacc[0][j], sacc[1][j]);
            if (__any(lmax > m_run[j] + RESCALE_THR)) {
                float mt = lmax;
#pragma unroll
                for (int off = 1; off < 16; off <<= 1)
                    mt = fmaxf(mt, __shfl_xor(mt, off));
                const float mn = fmaxf(m_run[j], mt);
                const float alpha = __expf(m_run[j] - mn);
                m_run[j] = mn;
                l_part[j] *= alpha;
#pragma unroll
                for (int n2 = 0; n2 < 8; ++n2) acc[n2][j] *= alpha;
            }
            float ls = 0.f;
#pragma unroll
            for (int n = 0; n < 2; ++n) {
                float p = __expf(sacc[n][j] - m_run[j]);
                sacc[n][j] = p;
                ls += p;
            }
            l_part[j] += ls;
        }

        // ---- P -> per-wave LDS [16 r][32 tok] bf16, row 64B, swz (r&3)<<4
#pragma unroll
        for (int n = 0; n < 2; ++n)
#pragma unroll
            for (int j = 0; j < 4; ++j) {
                const int r = lhi * 4 + j;
                const uint_t byte = (uint_t)(r * 64)
                    + (((uint_t)((n * 16 + l15) * 2)) ^ ((uint_t)((r & 3) << 4)));
                *(ushort_t*)(pb + byte) = f2bf(sacc[n][j]);
            }

        // ---- O += P V (k=32: single A fragment)
        {
            const uint_t pbyte = (uint_t)(l15 * 64)
                + (((uint_t)(lhi * 16)) ^ ((uint_t)((l15 & 3) << 4)));
            short8 pa = *(const short8*)(pb + pbyte);
#pragma unroll
            for (int n2 = 0; n2 < 8; ++n2) {
                const int dim = n2 * 16 + l15;
                const uint_t vbyte = (uint_t)(dim * 64)
                    + (((uint_t)(lhi * 16)) ^ ((uint_t)((dim & 3) << 4)));
                short8 vbf = *(const short8*)(vbuf + vbyte);
                acc[n2] = __builtin_amdgcn_mfma_f32_16x16x32_bf16(pa, vbf, acc[n2], 0, 0, 0);
            }
        }

        if (pf) __syncthreads();   // drains gll (vmcnt) + publishes next tile
    }

    // ---- epilogue
#pragma unroll
    for (int j = 0; j < 4; ++j) {
        float lsum = l_part[j];
#pragma unroll
        for (int off = 1; off < 16; off <<= 1)
            lsum += __shfl_xor(lsum, off);
        const int row64 = rg * 16 + lhi * 4 + j;
        const int qg    = qt * 64 + row64;
        if (mode == 0) {
            const float inv = 1.0f / lsum;
            float* dst = out + (size_t)qg * Q_STRIDE + h * 128;
#pragma unroll
            for (int n2 = 0; n2 < 8; ++n2)
                dst[n2 * 16 + l15] = acc[n2][j] * inv;
        } else {
            const int idx = ((qt - 8) * 32 + h) * 64 + row64;
            if (mode == 1) {
                float* dst = out + (size_t)qg * Q_STRIDE + h * 128;
#pragma unroll
                for (int n2 = 0; n2 < 8; ++n2)
                    dst[n2 * 16 + l15] = acc[n2][j];   // unnormalized
                if (l15 == 0) {
                    float* ml = (float*)(wsb + ML0_OFF) + (size_t)idx * 2;
                    ml[0] = m_run[j]; ml[1] = lsum;
                }
            } else {
                ushort_t* dst = (ushort_t*)(wsb + ACC1_OFF) + (size_t)idx * 128;
#pragma unroll
                for (int n2 = 0; n2 < 8; ++n2)
                    dst[n2 * 16 + l15] = f2bf(acc[n2][j]);
                if (l15 == 0) {
                    float* ml = (float*)(wsb + ML1_OFF) + (size_t)idx * 2;
                    ml[0] = m_run[j]; ml[1] = lsum;
                }
            }
        }
    }
}

// ---------------- combine (qt>=8 rows only) ----------------
__launch_bounds__(256)
__global__ void attn_combine(float* __restrict__ out, const char* __restrict__ wsb)
{
    const int pid = blockIdx.x;           // 256 = (qt-8)*32 + h
    const int qt = 8 + (pid >> 5);
    const int h  = pid & 31;
    const int tid = threadIdx.x;
    const int d4  = (tid & 31) * 4;
    const float* ml0b = (const float*)(wsb + ML0_OFF);
    const float* ml1b = (const float*)(wsb + ML1_OFF);
    const ushort_t* a1b = (const ushort_t*)(wsb + ACC1_OFF);

#pragma unroll
    for (int p = 0; p < 8; ++p) {
        const int r = (tid >> 5) + p * 8;            // row 0..63
        const size_t idx = (size_t)pid * 64 + r;
        const float m1 = ml0b[idx * 2], l1 = ml0b[idx * 2 + 1];
        const float m2 = ml1b[idx * 2], l2 = ml1b[idx * 2 + 1];
        const float m  = fmaxf(m1, m2);
        const float a1 = __expf(m1 - m), a2 = __expf(m2 - m);
        const float inv = 1.0f / (l1 * a1 + l2 * a2);
        float* o = out + (size_t)(qt * 64 + r) * Q_STRIDE + h * 128 + d4;
        const ushort_t* y4 = a1b + idx * 128 + d4;
        float4 x = *(const float4*)o;
        x.x = (x.x * a1 + bf2f(y4[0]) * a2) * inv;
        x.y = (x.y * a1 + bf2f(y4[1]) * a2) * inv;
        x.z = (x.z * a1 + bf2f(y4[2]) * a2) * inv;
        x.w = (x.w * a1 + bf2f(y4[3]) * a2) * inv;
        *(float4*)o = x;
    }
}

extern "C" void kernel_launch(void* const* d_in, const int* in_sizes, int n_in,
                              void* d_out, int out_size, void* d_ws, size_t ws_size,
                              hipStream_t stream) {
    const float* q   = (const float*)d_in[0];
    // d_in[1] (k) and d_in[2] (v) are dead under the reference's causal mask.
    const float* kvc = (const float*)d_in[3];
    const int*   bt  = (const int*)d_in[4];
    float* out = (float*)d_out;
    char*  wsb = (char*)d_ws;
    prep_kv<<<dim3(128), dim3(256), 0, stream>>>(kvc, bt, wsb);
    attn_main<<<dim3(768), dim3(256), 0, stream>>>(q, wsb, out, wsb);
    attn_combine<<<dim3(256), dim3(256), 0, stream>>>(out, wsb);
}